// Round 9
// baseline (427.540 us; speedup 1.0000x reference)
//
#include <hip/hip_runtime.h>
#include <hip/hip_bf16.h>

// ---------------- problem constants ----------------
constexpr int Bg  = 8;       // graphs
constexpr int Nn  = 1024;    // nodes per graph
constexpr int Cc  = 256;     // channels
constexpr int Hh  = 8;       // heads
constexpr int DKh = 32;      // head dim
constexpr int Ee  = 131072;  // edges
constexpr int BNn = Bg * Nn; // 8192 total nodes
constexpr int MSPLIT = 2;    // attention m-range split (occupancy)
constexpr int MCH = Nn / MSPLIT;
#define EPSV 1e-5f

typedef __attribute__((ext_vector_type(8))) short bf16x8;
typedef __attribute__((ext_vector_type(4))) float f32x4;

static __device__ __forceinline__ unsigned short f2b(float v) {
    __hip_bfloat16 h = __float2bfloat16(v);
    return __builtin_bit_cast(unsigned short, h);
}
static __device__ __forceinline__ bf16x8 ldb8(const unsigned short* p) {
    return *(const bf16x8*)p;
}

// ---------------- x -> bf16 into xcat[n][0:256] (row stride 512) ----------------
__global__ __launch_bounds__(256) void xconv_k(
    const float* __restrict__ x, unsigned short* __restrict__ xcat)
{
    int i = (blockIdx.x * 256 + threadIdx.x) * 4;
    float4 v = *(const float4*)(x + i);
    int r = i >> 8, c = i & 255;
    unsigned short* d = xcat + (size_t)r * 512 + c;
    d[0] = f2b(v.x); d[1] = f2b(v.y); d[2] = f2b(v.z); d[3] = f2b(v.w);
}

// ---------------- weight transpose+convert ----------------
__global__ __launch_bounds__(256) void wconv_k(
    const float* __restrict__ Wr, const float* __restrict__ Wn,
    const float* __restrict__ Wq, const float* __restrict__ Wk,
    const float* __restrict__ Wv, const float* __restrict__ Wo,
    const float* __restrict__ W1, const float* __restrict__ W2,
    unsigned short* __restrict__ WcatT,
    unsigned short* __restrict__ WqT, unsigned short* __restrict__ WkT,
    unsigned short* __restrict__ WvT, unsigned short* __restrict__ WoT,
    unsigned short* __restrict__ W1T, unsigned short* __restrict__ W2T)
{
    int idx = blockIdx.x * 256 + threadIdx.x;
    if (idx < 131072) {                      // WcatT [256][512]
        int n = idx >> 9, k = idx & 511;
        float v = (k < 256) ? Wr[k * 256 + n] : Wn[(k - 256) * 256 + n];
        WcatT[(size_t)n * 512 + k] = f2b(v);
    } else if (idx < 393216) {               // q,k,v,o
        int l = idx - 131072;
        int wsel = l >> 16; l &= 65535;
        int n = l >> 8, kk = l & 255;
        const float* S = wsel == 0 ? Wq : wsel == 1 ? Wk : wsel == 2 ? Wv : Wo;
        unsigned short* D = wsel == 0 ? WqT : wsel == 1 ? WkT : wsel == 2 ? WvT : WoT;
        D[n * 256 + kk] = f2b(S[kk * 256 + n]);
    } else if (idx < 524288) {               // W1 [256][512] -> W1T [512][256]
        int l = idx - 393216;
        int n = l >> 8, kk = l & 255;
        W1T[l] = f2b(W1[kk * 512 + n]);
    } else {                                 // W2 [512][256] -> W2T [256][512]
        int l = idx - 524288;
        int n = l >> 9, kk = l & 511;
        W2T[l] = f2b(W2[kk * 256 + n]);
    }
}

// ---------------- CSR build ----------------
__global__ __launch_bounds__(256) void hist_k(
    const int* __restrict__ ei, int* __restrict__ deg)
{
    int e = blockIdx.x * 256 + threadIdx.x;
    atomicAdd(&deg[ei[Ee + e]], 1);
}

__global__ __launch_bounds__(256) void scan_k(
    const int* __restrict__ deg, int* __restrict__ rowst, int* __restrict__ cursor)
{
    __shared__ int partial[256];
    int t = threadIdx.x;
    int local[32];
    int s = 0;
    #pragma unroll
    for (int i = 0; i < 32; ++i) { local[i] = deg[t * 32 + i]; s += local[i]; }
    partial[t] = s;
    __syncthreads();
    for (int off = 1; off < 256; off <<= 1) {
        int v = (t >= off) ? partial[t - off] : 0;
        __syncthreads();
        partial[t] += v;
        __syncthreads();
    }
    int base = partial[t] - s;
    #pragma unroll
    for (int i = 0; i < 32; ++i) {
        int idx = t * 32 + i;
        rowst[idx] = base;
        cursor[idx] = base;
        base += local[i];
    }
    if (t == 255) rowst[8192] = base;
}

__global__ __launch_bounds__(256) void place_k(
    const int* __restrict__ ei, int* __restrict__ cursor, int* __restrict__ eidx)
{
    int e = blockIdx.x * 256 + threadIdx.x;
    int s = ei[e], d = ei[Ee + e];
    int pos = atomicAdd(&cursor[d], 1);
    eidx[pos] = s;
}

// ---------------- gather: aggx[n] = sum_{e: dst=n} x[src_e] ----------------
__global__ __launch_bounds__(256) void gather_k(
    const float* __restrict__ x, const int* __restrict__ rowst,
    const int* __restrict__ eidx, unsigned short* __restrict__ xcat)
{
    int n = blockIdx.x, c = threadIdx.x;
    int b0 = rowst[n], b1 = rowst[n + 1];
    float acc = 0.f;
    for (int i = b0; i < b1; ++i) {
        int s = eidx[i];
        acc += x[(size_t)s * Cc + c];
    }
    xcat[(size_t)n * 512 + 256 + c] = f2b(acc);
}

// ---------------- MFMA GEMM, 32x64 tile ----------------
// out = maybe_relu( oscale*(A_bf16[M,K](lda) @ WT^T + bias?) + add1? + add2? )
// 4 waves = 2 row-halves x 2 col-halves; per wave 16x32 (2 acc tiles).
// Grid (N/64, M/32) -> 4 blocks/CU, 16 waves/CU: TLP hides the K-loop's
// global-load latency (R8 post-mortem: 2 blocks/CU 2x2 layout was latency-bound).
__global__ __launch_bounds__(256, 4) void gemm_mfma_k(
    const unsigned short* __restrict__ A, const unsigned short* __restrict__ WT,
    const float* __restrict__ bias, const float* __restrict__ add1,
    const float* __restrict__ add2, float* __restrict__ outf,
    unsigned short* __restrict__ outb,
    int M, int K, int lda, int N, int relu, float oscale)
{
    const int t = threadIdx.x;
    const int wave = t >> 6, lane = t & 63;
    const int tl = lane & 15, g = lane >> 4;
    const int wr = wave >> 1, wc = wave & 1;
    const int m0 = blockIdx.y * 32, n0 = blockIdx.x * 64;

    f32x4 acc[2] = {};

    const unsigned short* a0 = A  + (size_t)(m0 + wr * 16 + tl) * lda + g * 8;
    const unsigned short* b0 = WT + (size_t)(n0 + wc * 32 + tl) * K + g * 8;
    const unsigned short* b1 = b0 + (size_t)16 * K;

    for (int k0 = 0; k0 < K; k0 += 32) {
        bf16x8 af  = ldb8(a0 + k0);
        bf16x8 bf0 = ldb8(b0 + k0), bf1 = ldb8(b1 + k0);
        acc[0] = __builtin_amdgcn_mfma_f32_16x16x32_bf16(af, bf0, acc[0], 0, 0, 0);
        acc[1] = __builtin_amdgcn_mfma_f32_16x16x32_bf16(af, bf1, acc[1], 0, 0, 0);
    }

    #pragma unroll
    for (int c16 = 0; c16 < 2; ++c16)
        #pragma unroll
        for (int reg = 0; reg < 4; ++reg) {
            int row = m0 + wr * 16 + g * 4 + reg;
            int col = n0 + wc * 32 + c16 * 16 + tl;
            float v = acc[c16][reg];
            if (bias) v += bias[col];
            v *= oscale;
            size_t idx = (size_t)row * N + col;
            if (add1) v += add1[idx];
            if (add2) v += add2[idx];
            if (relu) v = fmaxf(v, 0.f);
            if (outf) outf[idx] = v;
            if (outb) outb[idx] = f2b(v);
        }
}

// ---------------- fused QKV GEMM: N=768 = [q|k|v] ----------------
// Same 32x64 tiling; epilogue routes per 256-col segment (block-uniform):
// q -> qb (scaled by QSCALE), k -> kb, v -> vTb transposed [b,h,d,n].
__global__ __launch_bounds__(256, 4) void qkv_gemm_k(
    const unsigned short* __restrict__ A, const unsigned short* __restrict__ WT,
    const float* __restrict__ bq, const float* __restrict__ bk,
    const float* __restrict__ bv,
    unsigned short* __restrict__ qb, unsigned short* __restrict__ kb,
    unsigned short* __restrict__ vTb, float qscale)
{
    const int t = threadIdx.x;
    const int wave = t >> 6, lane = t & 63;
    const int tl = lane & 15, g = lane >> 4;
    const int wr = wave >> 1, wc = wave & 1;
    const int m0 = blockIdx.y * 32, n0 = blockIdx.x * 64;
    const int which = n0 >> 8;               // 0:q 1:k 2:v (tile never straddles)
    const int K = 256, lda = 512;

    f32x4 acc[2] = {};

    const unsigned short* a0 = A  + (size_t)(m0 + wr * 16 + tl) * lda + g * 8;
    const unsigned short* b0 = WT + (size_t)(n0 + wc * 32 + tl) * K + g * 8;
    const unsigned short* b1 = b0 + (size_t)16 * K;

    for (int k0 = 0; k0 < K; k0 += 32) {
        bf16x8 af  = ldb8(a0 + k0);
        bf16x8 bf0 = ldb8(b0 + k0), bf1 = ldb8(b1 + k0);
        acc[0] = __builtin_amdgcn_mfma_f32_16x16x32_bf16(af, bf0, acc[0], 0, 0, 0);
        acc[1] = __builtin_amdgcn_mfma_f32_16x16x32_bf16(af, bf1, acc[1], 0, 0, 0);
    }

    const float* bias = which == 0 ? bq : which == 1 ? bk : bv;
    const float sc = which == 0 ? qscale : 1.f;

    #pragma unroll
    for (int c16 = 0; c16 < 2; ++c16)
        #pragma unroll
        for (int reg = 0; reg < 4; ++reg) {
            int row = m0 + wr * 16 + g * 4 + reg;
            int col = (n0 & 255) + wc * 32 + c16 * 16 + tl;   // 0..255 within segment
            float v = (acc[c16][reg] + bias[col]) * sc;
            if (which == 0) {
                qb[(size_t)row * Cc + col] = f2b(v);
            } else if (which == 1) {
                kb[(size_t)row * Cc + col] = f2b(v);
            } else {
                int bg = row >> 10, n = row & 1023;
                int hh = col >> 5,  d = col & 31;
                vTb[((size_t)((bg * Hh + hh) * DKh + d)) * Nn + n] = f2b(v);
            }
        }
}

// ---------------- BN stats ----------------
__global__ __launch_bounds__(256) void bn_stats_k(
    const float* __restrict__ h, float* __restrict__ gsum, float* __restrict__ gsq)
{
    int ch = threadIdx.x;
    int r0 = blockIdx.x * 32;
    float s = 0.f, s2 = 0.f;
    for (int r = r0; r < r0 + 32; ++r) {
        float v = h[(size_t)r * Cc + ch];
        s += v; s2 += v * v;
    }
    atomicAdd(&gsum[ch], s);
    atomicAdd(&gsq[ch], s2);
}

// ---------------- BN apply ----------------
__global__ __launch_bounds__(256) void bn_apply_k(
    const float* __restrict__ h, const float* __restrict__ gsum,
    const float* __restrict__ gsq, const float* __restrict__ gamma,
    const float* __restrict__ beta, const float* __restrict__ add,
    float* __restrict__ outf, unsigned short* __restrict__ outb)
{
    size_t idx = (size_t)blockIdx.x * 256 + threadIdx.x;
    int ch = (int)(idx & (Cc - 1));
    float m   = gsum[ch] * (1.f / BNn);
    float var = gsq[ch] * (1.f / BNn) - m * m;
    float sc  = rsqrtf(var + EPSV) * gamma[ch];
    float v = (h[idx] - m) * sc + beta[ch];
    if (add) v += add[idx];
    if (outf) outf[idx] = v;
    if (outb) outb[idx] = f2b(v);
}

// ---------------- MFMA flash attention, transposed scores, m-split ----------------
// grid (Nn/16, MSPLIT, Bg), 512 threads = 8 waves; wave w = head w. Block owns
// Q rows n0..n0+15 for all heads over m-chunk mc. sph tile staged cooperatively
// into LDS (coalesced, shared by all 8 head-waves). Scores transposed
// (s^T = K·Q^T); no max subtraction (scores ~N(0,1)); denominator deferred;
// q pre-scaled by (1/sqrt(32))*log2(e), p = exp2(s*sph). Outputs UNNORMALIZED
// fp32 O-partials + lsum partials; attn_combine_k normalizes.
__global__ __launch_bounds__(512) void attn_k(
    const unsigned short* __restrict__ q, const unsigned short* __restrict__ k,
    const unsigned short* __restrict__ vT, const float* __restrict__ sph,
    float* __restrict__ opart, float* __restrict__ lpart)
{
    const int n0 = blockIdx.x * 16;
    const int mc = blockIdx.y;
    const int b  = blockIdx.z;
    const int t  = threadIdx.x;
    const int w  = t >> 6;          // wave = head
    const int lane = t & 63;
    const int tl = lane & 15, g = lane >> 4;

    __shared__ float Sph[16][68];               // sph tile [n][m], padded
    __shared__ unsigned short Ps[Hh][16][72];   // per-wave P tile (bf16)

    bf16x8 qf = ldb8(q + ((size_t)(b * Nn + n0 + tl)) * Cc + w * DKh + g * 8);

    float lsum = 0.f;
    f32x4 oacc[2] = {};

    const unsigned short* kbase = k + ((size_t)(b * Nn) + tl) * Cc + w * DKh + g * 8;
    const unsigned short* vbase = vT + ((size_t)((b * Hh + w) * DKh) + tl) * Nn + g * 8;
    const float* sbase = sph + ((size_t)b * Nn + n0) * Nn;

    for (int m0 = mc * MCH; m0 < mc * MCH + MCH; m0 += 64) {
        __syncthreads();   // prev iter's Sph reads complete
        {
            int r1 = t >> 6, c1 = t & 63;
            Sph[r1][c1]     = sbase[(size_t)r1 * Nn + m0 + c1];
            Sph[r1 + 8][c1] = sbase[(size_t)(r1 + 8) * Nn + m0 + c1];
        }
        __syncthreads();   // Sph ready

        f32x4 st[4];
        #pragma unroll
        for (int mg = 0; mg < 4; ++mg) {
            bf16x8 ka = ldb8(kbase + (size_t)(m0 + mg * 16) * Cc);
            f32x4 z = {0.f, 0.f, 0.f, 0.f};
            st[mg] = __builtin_amdgcn_mfma_f32_16x16x32_bf16(ka, qf, z, 0, 0, 0);
        }

        #pragma unroll
        for (int mg = 0; mg < 4; ++mg) {
            float4 sp = *(const float4*)&Sph[tl][mg * 16 + g * 4];
            float p0 = exp2f(st[mg][0] * sp.x);
            float p1 = exp2f(st[mg][1] * sp.y);
            float p2 = exp2f(st[mg][2] * sp.z);
            float p3 = exp2f(st[mg][3] * sp.w);
            lsum += (p0 + p1) + (p2 + p3);
            ushort4 pk;
            pk.x = f2b(p0); pk.y = f2b(p1); pk.z = f2b(p2); pk.w = f2b(p3);
            *(ushort4*)&Ps[w][tl][mg * 16 + g * 4] = pk;
        }

        #pragma unroll
        for (int ks = 0; ks < 2; ++ks) {
            bf16x8 pa = ldb8(&Ps[w][tl][ks * 32 + g * 8]);
            #pragma unroll
            for (int cg = 0; cg < 2; ++cg) {
                bf16x8 vb = ldb8(vbase + (size_t)(cg * 16) * Nn + m0 + ks * 32);
                oacc[cg] = __builtin_amdgcn_mfma_f32_16x16x32_bf16(pa, vb, oacc[cg], 0, 0, 0);
            }
        }
    }

    lsum += __shfl_xor(lsum, 16);
    lsum += __shfl_xor(lsum, 32);
    if (g == 0)
        lpart[((size_t)mc * BNn + b * Nn + n0 + tl) * Hh + w] = lsum;

    #pragma unroll
    for (int r = 0; r < 4; ++r)
        #pragma unroll
        for (int cg = 0; cg < 2; ++cg)
            opart[((size_t)mc * BNn + b * Nn + n0 + g * 4 + r) * Cc + w * DKh + cg * 16 + tl]
                = oacc[cg][r];
}

// ---------------- combine m-split partials: ob = (sum O_i) / (sum l_i) ----------------
__global__ __launch_bounds__(256) void attn_combine_k(
    const float* __restrict__ op0, const float* __restrict__ op1,
    const float* __restrict__ lpart, unsigned short* __restrict__ ob)
{
    size_t idx = (size_t)blockIdx.x * 256 + threadIdx.x;   // over BNn*Cc
    int row = (int)(idx >> 8);
    int h = (int)((idx & 255) >> 5);
    float o = op0[idx] + op1[idx];
    float l = lpart[(size_t)row * Hh + h] + lpart[((size_t)BNn + row) * Hh + h];
    ob[idx] = f2b(o / l);
}

// ---------------- launch ----------------
extern "C" void kernel_launch(void* const* d_in, const int* in_sizes, int n_in,
                              void* d_out, int out_size, void* d_ws, size_t ws_size,
                              hipStream_t stream)
{
    const float* x   = (const float*)d_in[0];
    const int*   ei  = (const int*)  d_in[1];
    const float* sph = (const float*)d_in[2];
    const float* Wr  = (const float*)d_in[3];
    const float* Wn  = (const float*)d_in[4];
    const float* Wq  = (const float*)d_in[5];
    const float* bq  = (const float*)d_in[6];
    const float* Wk  = (const float*)d_in[7];
    const float* bk  = (const float*)d_in[8];
    const float* Wv  = (const float*)d_in[9];
    const float* bv  = (const float*)d_in[10];
    const float* Wo  = (const float*)d_in[11];
    const float* bo  = (const float*)d_in[12];
    const float* W1  = (const float*)d_in[13];
    const float* b1  = (const float*)d_in[14];
    const float* W2  = (const float*)d_in[15];
    const float* b2  = (const float*)d_in[16];
    const float* g1  = (const float*)d_in[17];
    const float* be1 = (const float*)d_in[18];
    const float* g2  = (const float*)d_in[19];
    const float* be2 = (const float*)d_in[20];
    const float* g3  = (const float*)d_in[21];
    const float* be3 = (const float*)d_in[22];
    float* out = (float*)d_out;

    const size_t SL = (size_t)BNn * Cc;  // 2M elements

    float* ws = (float*)d_ws;
    float* s1 = ws;                  // outsum (fp32); also attn O-partial chunk 0
    float* s2 = s1 + SL;             // h1pre -> h2pre -> out2; also O-partial chunk 1
    float* s3 = s2 + SL;             // h1
    float* stats = s3 + SL;          // 512 floats

    int* deg    = (int*)(stats + 512);
    int* rowst  = deg + 8192;
    int* cursor = rowst + 8256;
    int* eidx   = cursor + 8192;

    unsigned short* xcat = (unsigned short*)(eidx + 131072); // [8192][512]; reused as hid
    unsigned short* qb   = xcat + 2 * SL;
    unsigned short* kb   = qb + SL;                          // reused as osb
    unsigned short* vTb  = kb + SL;
    unsigned short* ob   = vTb + SL;
    unsigned short* osb  = kb;
    unsigned short* hid  = xcat;

    unsigned short* WcatT = ob + SL;          // 256x512
    unsigned short* WqT   = WcatT + 131072;   // WqT|WkT|WvT contiguous = [768][256]
    unsigned short* WkT   = WqT + 65536;
    unsigned short* WvT   = WkT + 65536;
    unsigned short* WoT   = WvT + 65536;
    unsigned short* W1T   = WoT + 65536;
    unsigned short* W2T   = W1T + 131072;
    float* lpart = (float*)(W2T + 131072);    // [MSPLIT][BNn][Hh] fp32

    // GEMM grids: (N/64, M/32)
    dim3 gN256(4, 256);
    dim3 gN512(8, 256);
    dim3 gQKV(12, 256);

    // scale/sqrt(DK) * log2(e), folded into Q projection; attn uses exp2
    const float QSCALE = 0.17677669529663687f * 1.4426950408889634f;

    // 0) converts + CSR build + gather
    xconv_k<<<2048, 256, 0, stream>>>(x, xcat);
    wconv_k<<<2560, 256, 0, stream>>>(Wr, Wn, Wq, Wk, Wv, Wo, W1, W2,
                                      WcatT, WqT, WkT, WvT, WoT, W1T, W2T);
    hipMemsetAsync(deg, 0, 8192 * sizeof(int), stream);
    hist_k<<<Ee / 256, 256, 0, stream>>>(ei, deg);
    scan_k<<<1, 256, 0, stream>>>(deg, rowst, cursor);
    place_k<<<Ee / 256, 256, 0, stream>>>(ei, cursor, eidx);
    gather_k<<<BNn, 256, 0, stream>>>(x, rowst, eidx, xcat);

    // 1) h1pre = [x|aggx] @ [Wr;Wn]^T + x   (K=512)
    gemm_mfma_k<<<gN256, 256, 0, stream>>>(xcat, WcatT, nullptr, x, nullptr,
                                           s2, nullptr, BNn, 512, 512, Cc, 0, 1.f);
    // 2) h1 = BN1(h1pre) -> s3
    hipMemsetAsync(stats, 0, 512 * sizeof(float), stream);
    bn_stats_k<<<256, 256, 0, stream>>>(s2, stats, stats + 256);
    bn_apply_k<<<BNn, 256, 0, stream>>>(s2, stats, stats + 256, g1, be1, nullptr, s3, nullptr);
    // 3) fused q,k,v projection (one GEMM, N=768)
    qkv_gemm_k<<<gQKV, 256, 0, stream>>>(xcat, WqT, bq, bk, bv, qb, kb, vTb, QSCALE);
    // 4) attention -> O-partials in s1(chunk0)/s2(chunk1) + lpart, then combine -> ob
    attn_k<<<dim3(Nn / 16, MSPLIT, Bg), 512, 0, stream>>>(qb, kb, vTb, sph, s1, lpart);
    attn_combine_k<<<(int)(SL / 256), 256, 0, stream>>>(s1, s2, lpart, ob);
    // 5) h2pre = o @ Wo + bo + x -> s2
    gemm_mfma_k<<<gN256, 256, 0, stream>>>(ob, WoT, bo, x, nullptr,
                                           s2, nullptr, BNn, Cc, Cc, Cc, 0, 1.f);
    // 6) outsum = BN2(h2pre) + h1 -> s1 (fp32) + osb (bf16)
    hipMemsetAsync(stats, 0, 512 * sizeof(float), stream);
    bn_stats_k<<<256, 256, 0, stream>>>(s2, stats, stats + 256);
    bn_apply_k<<<BNn, 256, 0, stream>>>(s2, stats, stats + 256, g2, be2, s3, s1, osb);
    // 7) hidden = relu(outsum @ W1 + b1) -> hid (bf16)
    gemm_mfma_k<<<gN512, 256, 0, stream>>>(osb, W1T, b1, nullptr, nullptr,
                                           nullptr, hid, BNn, Cc, Cc, 2 * Cc, 1, 1.f);
    // 8) out2 = hidden @ W2 + b2 + outsum -> s2
    gemm_mfma_k<<<gN256, 256, 0, stream>>>(hid, W2T, b2, s1, nullptr,
                                           s2, nullptr, BNn, 2 * Cc, 2 * Cc, Cc, 0, 1.f);
    // 9) d_out = BN3(out2)
    hipMemsetAsync(stats, 0, 512 * sizeof(float), stream);
    bn_stats_k<<<256, 256, 0, stream>>>(s2, stats, stats + 256);
    bn_apply_k<<<BNn, 256, 0, stream>>>(s2, stats, stats + 256, g3, be3, nullptr, out, nullptr);
}

// Round 10
// 414.628 us; speedup vs baseline: 1.0311x; 1.0311x over previous
//
#include <hip/hip_runtime.h>
#include <hip/hip_bf16.h>

// ---------------- problem constants ----------------
constexpr int Bg  = 8;       // graphs
constexpr int Nn  = 1024;    // nodes per graph
constexpr int Cc  = 256;     // channels
constexpr int Hh  = 8;       // heads
constexpr int DKh = 32;      // head dim
constexpr int Ee  = 131072;  // edges
constexpr int BNn = Bg * Nn; // 8192 total nodes
constexpr int MSPLIT = 2;    // attention m-range split (occupancy)
constexpr int MCH = Nn / MSPLIT;
#define EPSV 1e-5f

typedef __attribute__((ext_vector_type(8))) short bf16x8;
typedef __attribute__((ext_vector_type(4))) float f32x4;

static __device__ __forceinline__ unsigned short f2b(float v) {
    __hip_bfloat16 h = __float2bfloat16(v);
    return __builtin_bit_cast(unsigned short, h);
}
static __device__ __forceinline__ bf16x8 ldb8(const unsigned short* p) {
    return *(const bf16x8*)p;
}

// ---------------- fused prep: xconv + wconv + hist (one dispatch) ----------------
// blocks [0,2048): x -> bf16 into xcat[n][0:256] (row stride 512)
// blocks [2048,4608): weight transpose+convert
// blocks [4608,5120): degree histogram
__global__ __launch_bounds__(256) void prep_k(
    const float* __restrict__ x, unsigned short* __restrict__ xcat,
    const float* __restrict__ Wr, const float* __restrict__ Wn,
    const float* __restrict__ Wq, const float* __restrict__ Wk,
    const float* __restrict__ Wv, const float* __restrict__ Wo,
    const float* __restrict__ W1, const float* __restrict__ W2,
    unsigned short* __restrict__ WcatT,
    unsigned short* __restrict__ WqT, unsigned short* __restrict__ WkT,
    unsigned short* __restrict__ WvT, unsigned short* __restrict__ WoT,
    unsigned short* __restrict__ W1T, unsigned short* __restrict__ W2T,
    const int* __restrict__ ei, int* __restrict__ deg)
{
    int blk = blockIdx.x;
    if (blk < 2048) {
        int i = (blk * 256 + threadIdx.x) * 4;
        float4 v = *(const float4*)(x + i);
        int r = i >> 8, c = i & 255;
        unsigned short* d = xcat + (size_t)r * 512 + c;
        d[0] = f2b(v.x); d[1] = f2b(v.y); d[2] = f2b(v.z); d[3] = f2b(v.w);
    } else if (blk < 4608) {
        int idx = (blk - 2048) * 256 + threadIdx.x;
        if (idx < 131072) {                      // WcatT [256][512]
            int n = idx >> 9, k = idx & 511;
            float v = (k < 256) ? Wr[k * 256 + n] : Wn[(k - 256) * 256 + n];
            WcatT[(size_t)n * 512 + k] = f2b(v);
        } else if (idx < 393216) {               // q,k,v,o
            int l = idx - 131072;
            int wsel = l >> 16; l &= 65535;
            int n = l >> 8, kk = l & 255;
            const float* S = wsel == 0 ? Wq : wsel == 1 ? Wk : wsel == 2 ? Wv : Wo;
            unsigned short* D = wsel == 0 ? WqT : wsel == 1 ? WkT : wsel == 2 ? WvT : WoT;
            D[n * 256 + kk] = f2b(S[kk * 256 + n]);
        } else if (idx < 524288) {               // W1 [256][512] -> W1T [512][256]
            int l = idx - 393216;
            int n = l >> 8, kk = l & 255;
            W1T[l] = f2b(W1[kk * 512 + n]);
        } else {                                 // W2 [512][256] -> W2T [256][512]
            int l = idx - 524288;
            int n = l >> 9, kk = l & 511;
            W2T[l] = f2b(W2[kk * 256 + n]);
        }
    } else {
        int e = (blk - 4608) * 256 + threadIdx.x;
        atomicAdd(&deg[ei[Ee + e]], 1);
    }
}

// ---------------- CSR scan / place / gather ----------------
__global__ __launch_bounds__(256) void scan_k(
    const int* __restrict__ deg, int* __restrict__ rowst, int* __restrict__ cursor)
{
    __shared__ int partial[256];
    int t = threadIdx.x;
    int local[32];
    int s = 0;
    #pragma unroll
    for (int i = 0; i < 32; ++i) { local[i] = deg[t * 32 + i]; s += local[i]; }
    partial[t] = s;
    __syncthreads();
    for (int off = 1; off < 256; off <<= 1) {
        int v = (t >= off) ? partial[t - off] : 0;
        __syncthreads();
        partial[t] += v;
        __syncthreads();
    }
    int base = partial[t] - s;
    #pragma unroll
    for (int i = 0; i < 32; ++i) {
        int idx = t * 32 + i;
        rowst[idx] = base;
        cursor[idx] = base;
        base += local[i];
    }
    if (t == 255) rowst[8192] = base;
}

__global__ __launch_bounds__(256) void place_k(
    const int* __restrict__ ei, int* __restrict__ cursor, int* __restrict__ eidx)
{
    int e = blockIdx.x * 256 + threadIdx.x;
    int s = ei[e], d = ei[Ee + e];
    int pos = atomicAdd(&cursor[d], 1);
    eidx[pos] = s;
}

__global__ __launch_bounds__(256) void gather_k(
    const float* __restrict__ x, const int* __restrict__ rowst,
    const int* __restrict__ eidx, unsigned short* __restrict__ xcat)
{
    int n = blockIdx.x, c = threadIdx.x;
    int b0 = rowst[n], b1 = rowst[n + 1];
    float acc = 0.f;
    for (int i = b0; i < b1; ++i) {
        int s = eidx[i];
        acc += x[(size_t)s * Cc + c];
    }
    xcat[(size_t)n * 512 + 256 + c] = f2b(acc);
}

// ---------------- MFMA GEMM, 32x64 tile, optional fused BN-stats ----------------
// out = maybe_relu( oscale*(A @ WT^T + bias?) + add1? ); if gsum: accumulate
// per-channel sum/sumsq of the (pre-relu) output into global stats via LDS
// reduction + 2 atomics/channel/block (replaces standalone bn_stats pass).
__global__ __launch_bounds__(256, 4) void gemm_mfma_k(
    const unsigned short* __restrict__ A, const unsigned short* __restrict__ WT,
    const float* __restrict__ bias, const float* __restrict__ add1,
    float* __restrict__ outf, unsigned short* __restrict__ outb,
    float* __restrict__ gsum, float* __restrict__ gsq,
    int M, int K, int lda, int N, int relu, float oscale)
{
    const int t = threadIdx.x;
    const int wave = t >> 6, lane = t & 63;
    const int tl = lane & 15, g = lane >> 4;
    const int wr = wave >> 1, wc = wave & 1;
    const int m0 = blockIdx.y * 32, n0 = blockIdx.x * 64;

    __shared__ float csum[64], csq[64];
    if (gsum) {
        if (t < 64) { csum[t] = 0.f; csq[t] = 0.f; }
        __syncthreads();
    }

    f32x4 acc[2] = {};

    const unsigned short* a0 = A  + (size_t)(m0 + wr * 16 + tl) * lda + g * 8;
    const unsigned short* b0 = WT + (size_t)(n0 + wc * 32 + tl) * K + g * 8;
    const unsigned short* b1 = b0 + (size_t)16 * K;

    for (int k0 = 0; k0 < K; k0 += 32) {
        bf16x8 af  = ldb8(a0 + k0);
        bf16x8 bf0 = ldb8(b0 + k0), bf1 = ldb8(b1 + k0);
        acc[0] = __builtin_amdgcn_mfma_f32_16x16x32_bf16(af, bf0, acc[0], 0, 0, 0);
        acc[1] = __builtin_amdgcn_mfma_f32_16x16x32_bf16(af, bf1, acc[1], 0, 0, 0);
    }

    #pragma unroll
    for (int c16 = 0; c16 < 2; ++c16) {
        int colL = wc * 32 + c16 * 16 + tl;
        int col  = n0 + colL;
        float ls = 0.f, lq = 0.f;
        #pragma unroll
        for (int reg = 0; reg < 4; ++reg) {
            int row = m0 + wr * 16 + g * 4 + reg;
            float v = acc[c16][reg];
            if (bias) v += bias[col];
            v *= oscale;
            size_t idx = (size_t)row * N + col;
            if (add1) v += add1[idx];
            ls += v; lq += v * v;
            if (relu) v = fmaxf(v, 0.f);
            if (outf) outf[idx] = v;
            if (outb) outb[idx] = f2b(v);
        }
        if (gsum) { atomicAdd(&csum[colL], ls); atomicAdd(&csq[colL], lq); }
    }
    if (gsum) {
        __syncthreads();
        if (t < 64) {
            atomicAdd(&gsum[n0 + t], csum[t]);
            atomicAdd(&gsq[n0 + t],  csq[t]);
        }
    }
}

// ---------------- fused QKV GEMM: N=768 = [q|k|v] ----------------
__global__ __launch_bounds__(256, 4) void qkv_gemm_k(
    const unsigned short* __restrict__ A, const unsigned short* __restrict__ WT,
    const float* __restrict__ bq, const float* __restrict__ bk,
    const float* __restrict__ bv,
    unsigned short* __restrict__ qb, unsigned short* __restrict__ kb,
    unsigned short* __restrict__ vTb, float qscale)
{
    const int t = threadIdx.x;
    const int wave = t >> 6, lane = t & 63;
    const int tl = lane & 15, g = lane >> 4;
    const int wr = wave >> 1, wc = wave & 1;
    const int m0 = blockIdx.y * 32, n0 = blockIdx.x * 64;
    const int which = n0 >> 8;               // 0:q 1:k 2:v
    const int K = 256, lda = 512;

    f32x4 acc[2] = {};

    const unsigned short* a0 = A  + (size_t)(m0 + wr * 16 + tl) * lda + g * 8;
    const unsigned short* b0 = WT + (size_t)(n0 + wc * 32 + tl) * K + g * 8;
    const unsigned short* b1 = b0 + (size_t)16 * K;

    for (int k0 = 0; k0 < K; k0 += 32) {
        bf16x8 af  = ldb8(a0 + k0);
        bf16x8 bf0 = ldb8(b0 + k0), bf1 = ldb8(b1 + k0);
        acc[0] = __builtin_amdgcn_mfma_f32_16x16x32_bf16(af, bf0, acc[0], 0, 0, 0);
        acc[1] = __builtin_amdgcn_mfma_f32_16x16x32_bf16(af, bf1, acc[1], 0, 0, 0);
    }

    const float* bias = which == 0 ? bq : which == 1 ? bk : bv;
    const float sc = which == 0 ? qscale : 1.f;

    #pragma unroll
    for (int c16 = 0; c16 < 2; ++c16)
        #pragma unroll
        for (int reg = 0; reg < 4; ++reg) {
            int row = m0 + wr * 16 + g * 4 + reg;
            int col = (n0 & 255) + wc * 32 + c16 * 16 + tl;
            float v = (acc[c16][reg] + bias[col]) * sc;
            if (which == 0) {
                qb[(size_t)row * Cc + col] = f2b(v);
            } else if (which == 1) {
                kb[(size_t)row * Cc + col] = f2b(v);
            } else {
                int bg = row >> 10, n = row & 1023;
                int hh = col >> 5,  d = col & 31;
                vTb[((size_t)((bg * Hh + hh) * DKh + d)) * Nn + n] = f2b(v);
            }
        }
}

// ---------------- BN apply (single) ----------------
__global__ __launch_bounds__(256) void bn_apply_k(
    const float* __restrict__ h, const float* __restrict__ gsum,
    const float* __restrict__ gsq, const float* __restrict__ gamma,
    const float* __restrict__ beta, float* __restrict__ outf)
{
    size_t idx = (size_t)blockIdx.x * 256 + threadIdx.x;
    int ch = (int)(idx & (Cc - 1));
    float m   = gsum[ch] * (1.f / BNn);
    float var = gsq[ch] * (1.f / BNn) - m * m;
    float sc  = rsqrtf(var + EPSV) * gamma[ch];
    outf[idx] = (h[idx] - m) * sc + beta[ch];
}

// ---------------- fused BN1+BN2 apply: outsum = bn1(h1pre) + bn2(h2pre) ----------------
__global__ __launch_bounds__(256) void bn_apply12_k(
    const float* __restrict__ h1pre, const float* __restrict__ h2pre,
    const float* __restrict__ stats,   // [sum1|sq1|sum2|sq2] each 256
    const float* __restrict__ g1, const float* __restrict__ be1,
    const float* __restrict__ g2, const float* __restrict__ be2,
    float* __restrict__ outf, unsigned short* __restrict__ outb)
{
    size_t idx = (size_t)blockIdx.x * 256 + threadIdx.x;
    int ch = (int)(idx & (Cc - 1));
    float m1 = stats[ch] * (1.f / BNn);
    float v1 = stats[256 + ch] * (1.f / BNn) - m1 * m1;
    float s1 = rsqrtf(v1 + EPSV) * g1[ch];
    float m2 = stats[512 + ch] * (1.f / BNn);
    float v2 = stats[768 + ch] * (1.f / BNn) - m2 * m2;
    float s2 = rsqrtf(v2 + EPSV) * g2[ch];
    float v = (h1pre[idx] - m1) * s1 + be1[ch]
            + (h2pre[idx] - m2) * s2 + be2[ch];
    outf[idx] = v;
    outb[idx] = f2b(v);
}

// ---------------- MFMA flash attention, transposed scores, m-split ----------------
// grid (Nn/16, MSPLIT, Bg), 512 threads = 8 waves; wave w = head w. sph tile
// staged cooperatively in LDS; scores transposed (s^T = K·Q^T); no max
// subtraction; denominator deferred; q pre-scaled by (1/sqrt 32)*log2(e).
// Unnormalized fp32 O-partials (op0/op1 by m-chunk) + lsum partials.
__global__ __launch_bounds__(512) void attn_k(
    const unsigned short* __restrict__ q, const unsigned short* __restrict__ k,
    const unsigned short* __restrict__ vT, const float* __restrict__ sph,
    float* __restrict__ op0, float* __restrict__ op1, float* __restrict__ lpart)
{
    const int n0 = blockIdx.x * 16;
    const int mc = blockIdx.y;
    const int b  = blockIdx.z;
    const int t  = threadIdx.x;
    const int w  = t >> 6;
    const int lane = t & 63;
    const int tl = lane & 15, g = lane >> 4;

    __shared__ float Sph[16][68];
    __shared__ unsigned short Ps[Hh][16][72];

    bf16x8 qf = ldb8(q + ((size_t)(b * Nn + n0 + tl)) * Cc + w * DKh + g * 8);

    float lsum = 0.f;
    f32x4 oacc[2] = {};

    const unsigned short* kbase = k + ((size_t)(b * Nn) + tl) * Cc + w * DKh + g * 8;
    const unsigned short* vbase = vT + ((size_t)((b * Hh + w) * DKh) + tl) * Nn + g * 8;
    const float* sbase = sph + ((size_t)b * Nn + n0) * Nn;

    for (int m0 = mc * MCH; m0 < mc * MCH + MCH; m0 += 64) {
        __syncthreads();
        {
            int r1 = t >> 6, c1 = t & 63;
            Sph[r1][c1]     = sbase[(size_t)r1 * Nn + m0 + c1];
            Sph[r1 + 8][c1] = sbase[(size_t)(r1 + 8) * Nn + m0 + c1];
        }
        __syncthreads();

        f32x4 st[4];
        #pragma unroll
        for (int mg = 0; mg < 4; ++mg) {
            bf16x8 ka = ldb8(kbase + (size_t)(m0 + mg * 16) * Cc);
            f32x4 z = {0.f, 0.f, 0.f, 0.f};
            st[mg] = __builtin_amdgcn_mfma_f32_16x16x32_bf16(ka, qf, z, 0, 0, 0);
        }

        #pragma unroll
        for (int mg = 0; mg < 4; ++mg) {
            float4 sp = *(const float4*)&Sph[tl][mg * 16 + g * 4];
            float p0 = exp2f(st[mg][0] * sp.x);
            float p1 = exp2f(st[mg][1] * sp.y);
            float p2 = exp2f(st[mg][2] * sp.z);
            float p3 = exp2f(st[mg][3] * sp.w);
            lsum += (p0 + p1) + (p2 + p3);
            ushort4 pk;
            pk.x = f2b(p0); pk.y = f2b(p1); pk.z = f2b(p2); pk.w = f2b(p3);
            *(ushort4*)&Ps[w][tl][mg * 16 + g * 4] = pk;
        }

        #pragma unroll
        for (int ks = 0; ks < 2; ++ks) {
            bf16x8 pa = ldb8(&Ps[w][tl][ks * 32 + g * 8]);
            #pragma unroll
            for (int cg = 0; cg < 2; ++cg) {
                bf16x8 vb = ldb8(vbase + (size_t)(cg * 16) * Nn + m0 + ks * 32);
                oacc[cg] = __builtin_amdgcn_mfma_f32_16x16x32_bf16(pa, vb, oacc[cg], 0, 0, 0);
            }
        }
    }

    lsum += __shfl_xor(lsum, 16);
    lsum += __shfl_xor(lsum, 32);
    if (g == 0)
        lpart[((size_t)mc * BNn + b * Nn + n0 + tl) * Hh + w] = lsum;

    float* op = mc ? op1 : op0;
    #pragma unroll
    for (int r = 0; r < 4; ++r)
        #pragma unroll
        for (int cg = 0; cg < 2; ++cg)
            op[((size_t)(b * Nn + n0 + g * 4 + r)) * Cc + w * DKh + cg * 16 + tl]
                = oacc[cg][r];
}

// ---------------- combine m-split partials: ob = (sum O_i) / (sum l_i) ----------------
__global__ __launch_bounds__(256) void attn_combine_k(
    const float* __restrict__ op0, const float* __restrict__ op1,
    const float* __restrict__ lpart, unsigned short* __restrict__ ob)
{
    size_t idx = (size_t)blockIdx.x * 256 + threadIdx.x;   // over BNn*Cc
    int row = (int)(idx >> 8);
    int h = (int)((idx & 255) >> 5);
    float o = op0[idx] + op1[idx];
    float l = lpart[(size_t)row * Hh + h] + lpart[((size_t)BNn + row) * Hh + h];
    ob[idx] = f2b(o / l);
}

// ---------------- launch ----------------
extern "C" void kernel_launch(void* const* d_in, const int* in_sizes, int n_in,
                              void* d_out, int out_size, void* d_ws, size_t ws_size,
                              hipStream_t stream)
{
    const float* x   = (const float*)d_in[0];
    const int*   ei  = (const int*)  d_in[1];
    const float* sph = (const float*)d_in[2];
    const float* Wr  = (const float*)d_in[3];
    const float* Wn  = (const float*)d_in[4];
    const float* Wq  = (const float*)d_in[5];
    const float* bq  = (const float*)d_in[6];
    const float* Wk  = (const float*)d_in[7];
    const float* bk  = (const float*)d_in[8];
    const float* Wv  = (const float*)d_in[9];
    const float* bv  = (const float*)d_in[10];
    const float* Wo  = (const float*)d_in[11];
    const float* bo  = (const float*)d_in[12];
    const float* W1  = (const float*)d_in[13];
    const float* b1  = (const float*)d_in[14];
    const float* W2  = (const float*)d_in[15];
    const float* b2  = (const float*)d_in[16];
    const float* g1  = (const float*)d_in[17];
    const float* be1 = (const float*)d_in[18];
    const float* g2  = (const float*)d_in[19];
    const float* be2 = (const float*)d_in[20];
    const float* g3  = (const float*)d_in[21];
    const float* be3 = (const float*)d_in[22];
    float* out = (float*)d_out;

    const size_t SL = (size_t)BNn * Cc;  // 2M elements

    float* ws = (float*)d_ws;
    float* s1 = ws;                  // attn O-partial 0 -> outsum (fp32)
    float* s2 = s1 + SL;             // h1pre (alive until bn_apply12) -> out2
    float* s3 = s2 + SL;             // h2pre

    int*   deg      = (int*)(s3 + SL);          // 8192
    float* statsAll = (float*)(deg + 8192);     // 1536: sum1|sq1|sum2|sq2|sum3|sq3
    int*   rowst    = (int*)(statsAll + 1536);  // 8256
    int*   cursor   = rowst + 8256;             // 8192
    int*   eidx     = cursor + 8192;            // 131072

    unsigned short* xcat = (unsigned short*)(eidx + 131072); // [8192][512]; reused as
                                                             // opart1 (float) then hid
    unsigned short* qb   = xcat + 2 * SL;
    unsigned short* kb   = qb + SL;                          // reused as osb
    unsigned short* vTb  = kb + SL;
    unsigned short* ob   = vTb + SL;
    unsigned short* osb  = kb;
    unsigned short* hid  = xcat;
    float* opart1 = (float*)xcat;

    unsigned short* WcatT = ob + SL;          // 256x512
    unsigned short* WqT   = WcatT + 131072;   // WqT|WkT|WvT contiguous = [768][256]
    unsigned short* WkT   = WqT + 65536;
    unsigned short* WvT   = WkT + 65536;
    unsigned short* WoT   = WvT + 65536;
    unsigned short* W1T   = WoT + 65536;
    unsigned short* W2T   = W1T + 131072;
    float* lpart = (float*)(W2T + 131072);    // [MSPLIT][BNn][Hh] fp32

    dim3 gN256(4, 256);
    dim3 gN512(8, 256);
    dim3 gQKV(12, 256);

    const float QSCALE = 0.17677669529663687f * 1.4426950408889634f;

    // 1) zero deg + all BN stats in ONE memset (contiguous)
    hipMemsetAsync(deg, 0, (8192 + 1536) * sizeof(float), stream);
    // 2) fused converts + histogram
    prep_k<<<5120, 256, 0, stream>>>(x, xcat, Wr, Wn, Wq, Wk, Wv, Wo, W1, W2,
                                     WcatT, WqT, WkT, WvT, WoT, W1T, W2T, ei, deg);
    // 3-5) CSR scan / place / gather
    scan_k<<<1, 256, 0, stream>>>(deg, rowst, cursor);
    place_k<<<Ee / 256, 256, 0, stream>>>(ei, cursor, eidx);
    gather_k<<<BNn, 256, 0, stream>>>(x, rowst, eidx, xcat);
    // 6) h1pre = [x|aggx] @ [Wr;Wn]^T + x  (K=512) -> s2, + fused BN1 stats
    gemm_mfma_k<<<gN256, 256, 0, stream>>>(xcat, WcatT, nullptr, x,
                                           s2, nullptr, statsAll, statsAll + 256,
                                           BNn, 512, 512, Cc, 0, 1.f);
    // 7) fused q,k,v projection (one GEMM, N=768)
    qkv_gemm_k<<<gQKV, 256, 0, stream>>>(xcat, WqT, bq, bk, bv, qb, kb, vTb, QSCALE);
    // 8) attention -> O-partials (s1, xcat-as-float) + lpart
    attn_k<<<dim3(Nn / 16, MSPLIT, Bg), 512, 0, stream>>>(qb, kb, vTb, sph,
                                                          s1, opart1, lpart);
    // 9) combine -> ob (bf16)
    attn_combine_k<<<(int)(SL / 256), 256, 0, stream>>>(s1, opart1, lpart, ob);
    // 10) h2pre = o @ Wo + bo + x -> s3, + fused BN2 stats
    gemm_mfma_k<<<gN256, 256, 0, stream>>>(ob, WoT, bo, x,
                                           s3, nullptr, statsAll + 512, statsAll + 768,
                                           BNn, Cc, Cc, Cc, 0, 1.f);
    // 11) outsum = bn1(h1pre) + bn2(h2pre) -> s1 (fp32) + osb (bf16)
    bn_apply12_k<<<BNn, 256, 0, stream>>>(s2, s3, statsAll, g1, be1, g2, be2, s1, osb);
    // 12) hidden = relu(outsum @ W1 + b1) -> hid (bf16)
    gemm_mfma_k<<<gN512, 256, 0, stream>>>(osb, W1T, b1, nullptr,
                                           nullptr, hid, nullptr, nullptr,
                                           BNn, Cc, Cc, 2 * Cc, 1, 1.f);
    // 13) out2 = hidden @ W2 + b2 + outsum -> s2, + fused BN3 stats
    gemm_mfma_k<<<gN256, 256, 0, stream>>>(hid, W2T, b2, s1,
                                           s2, nullptr, statsAll + 1024, statsAll + 1280,
                                           BNn, 2 * Cc, 2 * Cc, Cc, 0, 1.f);
    // 14) d_out = BN3(out2)
    bn_apply_k<<<BNn, 256, 0, stream>>>(s2, statsAll + 1024, statsAll + 1280,
                                        g3, be3, out);
}

// Round 11
// 399.442 us; speedup vs baseline: 1.0703x; 1.0380x over previous
//
#include <hip/hip_runtime.h>
#include <hip/hip_bf16.h>

// ---------------- problem constants ----------------
constexpr int Bg  = 8;       // graphs
constexpr int Nn  = 1024;    // nodes per graph
constexpr int Cc  = 256;     // channels
constexpr int Hh  = 8;       // heads
constexpr int DKh = 32;      // head dim
constexpr int Ee  = 131072;  // edges
constexpr int BNn = Bg * Nn; // 8192 total nodes
constexpr int MSPLIT = 4;    // attention m-range split (occupancy)
constexpr int MCH = Nn / MSPLIT;
#define EPSV 1e-5f

typedef __attribute__((ext_vector_type(8))) short bf16x8;
typedef __attribute__((ext_vector_type(4))) float f32x4;

static __device__ __forceinline__ unsigned short f2b(float v) {
    __hip_bfloat16 h = __float2bfloat16(v);
    return __builtin_bit_cast(unsigned short, h);
}
static __device__ __forceinline__ bf16x8 ldb8(const unsigned short* p) {
    return *(const bf16x8*)p;
}

// ---------------- fused prep: xconv + wconv + hist ----------------
__global__ __launch_bounds__(256) void prep_k(
    const float* __restrict__ x, unsigned short* __restrict__ xcat,
    const float* __restrict__ Wr, const float* __restrict__ Wn,
    const float* __restrict__ Wq, const float* __restrict__ Wk,
    const float* __restrict__ Wv, const float* __restrict__ Wo,
    const float* __restrict__ W1, const float* __restrict__ W2,
    unsigned short* __restrict__ WcatT,
    unsigned short* __restrict__ WqT, unsigned short* __restrict__ WkT,
    unsigned short* __restrict__ WvT, unsigned short* __restrict__ WoT,
    unsigned short* __restrict__ W1T, unsigned short* __restrict__ W2T,
    const int* __restrict__ ei, int* __restrict__ deg)
{
    int blk = blockIdx.x;
    if (blk < 2048) {
        int i = (blk * 256 + threadIdx.x) * 4;
        float4 v = *(const float4*)(x + i);
        int r = i >> 8, c = i & 255;
        ushort4 pk;
        pk.x = f2b(v.x); pk.y = f2b(v.y); pk.z = f2b(v.z); pk.w = f2b(v.w);
        *(ushort4*)(xcat + (size_t)r * 512 + c) = pk;
    } else if (blk < 4608) {
        int idx = (blk - 2048) * 256 + threadIdx.x;
        if (idx < 131072) {                      // WcatT [256][512]
            int n = idx >> 9, k = idx & 511;
            float v = (k < 256) ? Wr[k * 256 + n] : Wn[(k - 256) * 256 + n];
            WcatT[(size_t)n * 512 + k] = f2b(v);
        } else if (idx < 393216) {               // q,k,v,o
            int l = idx - 131072;
            int wsel = l >> 16; l &= 65535;
            int n = l >> 8, kk = l & 255;
            const float* S = wsel == 0 ? Wq : wsel == 1 ? Wk : wsel == 2 ? Wv : Wo;
            unsigned short* D = wsel == 0 ? WqT : wsel == 1 ? WkT : wsel == 2 ? WvT : WoT;
            D[n * 256 + kk] = f2b(S[kk * 256 + n]);
        } else if (idx < 524288) {               // W1 [256][512] -> W1T [512][256]
            int l = idx - 393216;
            int n = l >> 8, kk = l & 255;
            W1T[l] = f2b(W1[kk * 512 + n]);
        } else {                                 // W2 [512][256] -> W2T [256][512]
            int l = idx - 524288;
            int n = l >> 9, kk = l & 511;
            W2T[l] = f2b(W2[kk * 256 + n]);
        }
    } else {
        int e = (blk - 4608) * 256 + threadIdx.x;
        atomicAdd(&deg[ei[Ee + e]], 1);
    }
}

// ---------------- CSR scan (coalesced, interleaved buckets) ----------------
// Thread t owns nodes {i*256+t}. Bucket ranges are disjoint but NOT in node
// order — gather uses rowst[n] + deg[n], so order is free.
__global__ __launch_bounds__(256) void scan_k(
    const int* __restrict__ deg, int* __restrict__ rowst, int* __restrict__ cursor)
{
    __shared__ int partial[256];
    int t = threadIdx.x;
    int local[32];
    int s = 0;
    #pragma unroll
    for (int i = 0; i < 32; ++i) { local[i] = deg[i * 256 + t]; s += local[i]; }
    partial[t] = s;
    __syncthreads();
    for (int off = 1; off < 256; off <<= 1) {
        int v = (t >= off) ? partial[t - off] : 0;
        __syncthreads();
        partial[t] += v;
        __syncthreads();
    }
    int base = partial[t] - s;
    #pragma unroll
    for (int i = 0; i < 32; ++i) {
        int n = i * 256 + t;
        rowst[n] = base;
        cursor[n] = base;
        base += local[i];
    }
}

__global__ __launch_bounds__(256) void place_k(
    const int* __restrict__ ei, int* __restrict__ cursor, int* __restrict__ eidx)
{
    int e = blockIdx.x * 256 + threadIdx.x;
    int s = ei[e], d = ei[Ee + e];
    int pos = atomicAdd(&cursor[d], 1);
    eidx[pos] = s;
}

// ---------------- gather: 1 wave/node, float4 channels, 4-edge ILP ----------------
__global__ __launch_bounds__(64) void gather_k(
    const float* __restrict__ x, const int* __restrict__ rowst,
    const int* __restrict__ deg, const int* __restrict__ eidx,
    unsigned short* __restrict__ xcat)
{
    int n = blockIdx.x;
    int c4 = threadIdx.x * 4;
    int b0 = rowst[n], d = deg[n];
    float4 acc = {0.f, 0.f, 0.f, 0.f};
    int i = 0;
    for (; i + 4 <= d; i += 4) {
        int s0 = eidx[b0 + i], s1 = eidx[b0 + i + 1];
        int s2 = eidx[b0 + i + 2], s3 = eidx[b0 + i + 3];
        float4 a0 = *(const float4*)(x + (size_t)s0 * Cc + c4);
        float4 a1 = *(const float4*)(x + (size_t)s1 * Cc + c4);
        float4 a2 = *(const float4*)(x + (size_t)s2 * Cc + c4);
        float4 a3 = *(const float4*)(x + (size_t)s3 * Cc + c4);
        acc.x += (a0.x + a1.x) + (a2.x + a3.x);
        acc.y += (a0.y + a1.y) + (a2.y + a3.y);
        acc.z += (a0.z + a1.z) + (a2.z + a3.z);
        acc.w += (a0.w + a1.w) + (a2.w + a3.w);
    }
    for (; i < d; ++i) {
        int s = eidx[b0 + i];
        float4 a = *(const float4*)(x + (size_t)s * Cc + c4);
        acc.x += a.x; acc.y += a.y; acc.z += a.z; acc.w += a.w;
    }
    ushort4 pk;
    pk.x = f2b(acc.x); pk.y = f2b(acc.y); pk.z = f2b(acc.z); pk.w = f2b(acc.w);
    *(ushort4*)(xcat + (size_t)n * 512 + 256 + c4) = pk;
}

// ---------------- MFMA GEMM, 32x64 tile, optional fused BN-stats ----------------
__global__ __launch_bounds__(256, 4) void gemm_mfma_k(
    const unsigned short* __restrict__ A, const unsigned short* __restrict__ WT,
    const float* __restrict__ bias, const float* __restrict__ add1,
    float* __restrict__ outf, unsigned short* __restrict__ outb,
    float* __restrict__ gsum, float* __restrict__ gsq,
    int M, int K, int lda, int N, int relu, float oscale)
{
    const int t = threadIdx.x;
    const int wave = t >> 6, lane = t & 63;
    const int tl = lane & 15, g = lane >> 4;
    const int wr = wave >> 1, wc = wave & 1;
    const int m0 = blockIdx.y * 32, n0 = blockIdx.x * 64;

    __shared__ float csum[64], csq[64];
    if (gsum) {
        if (t < 64) { csum[t] = 0.f; csq[t] = 0.f; }
        __syncthreads();
    }

    f32x4 acc[2] = {};

    const unsigned short* a0 = A  + (size_t)(m0 + wr * 16 + tl) * lda + g * 8;
    const unsigned short* b0 = WT + (size_t)(n0 + wc * 32 + tl) * K + g * 8;
    const unsigned short* b1 = b0 + (size_t)16 * K;

    for (int k0 = 0; k0 < K; k0 += 32) {
        bf16x8 af  = ldb8(a0 + k0);
        bf16x8 bf0 = ldb8(b0 + k0), bf1 = ldb8(b1 + k0);
        acc[0] = __builtin_amdgcn_mfma_f32_16x16x32_bf16(af, bf0, acc[0], 0, 0, 0);
        acc[1] = __builtin_amdgcn_mfma_f32_16x16x32_bf16(af, bf1, acc[1], 0, 0, 0);
    }

    #pragma unroll
    for (int c16 = 0; c16 < 2; ++c16) {
        int colL = wc * 32 + c16 * 16 + tl;
        int col  = n0 + colL;
        float ls = 0.f, lq = 0.f;
        #pragma unroll
        for (int reg = 0; reg < 4; ++reg) {
            int row = m0 + wr * 16 + g * 4 + reg;
            float v = acc[c16][reg];
            if (bias) v += bias[col];
            v *= oscale;
            size_t idx = (size_t)row * N + col;
            if (add1) v += add1[idx];
            ls += v; lq += v * v;
            if (relu) v = fmaxf(v, 0.f);
            if (outf) outf[idx] = v;
            if (outb) outb[idx] = f2b(v);
        }
        if (gsum) { atomicAdd(&csum[colL], ls); atomicAdd(&csq[colL], lq); }
    }
    if (gsum) {
        __syncthreads();
        if (t < 64) {
            atomicAdd(&gsum[n0 + t], csum[t]);
            atomicAdd(&gsq[n0 + t],  csq[t]);
        }
    }
}

// ---------------- fused QKV GEMM: N=768 = [q|k|v] ----------------
// v segment: epilogue stages the 32x64 tile in LDS and writes vTb [b,h,d,n]
// with coalesced 8B stores (direct per-lane 2B stores hit 16 lines/instr).
__global__ __launch_bounds__(256, 4) void qkv_gemm_k(
    const unsigned short* __restrict__ A, const unsigned short* __restrict__ WT,
    const float* __restrict__ bq, const float* __restrict__ bk,
    const float* __restrict__ bv,
    unsigned short* __restrict__ qb, unsigned short* __restrict__ kb,
    unsigned short* __restrict__ vTb, float qscale)
{
    const int t = threadIdx.x;
    const int wave = t >> 6, lane = t & 63;
    const int tl = lane & 15, g = lane >> 4;
    const int wr = wave >> 1, wc = wave & 1;
    const int m0 = blockIdx.y * 32, n0 = blockIdx.x * 64;
    const int which = n0 >> 8;               // 0:q 1:k 2:v
    const int K = 256, lda = 512;

    __shared__ unsigned short vtile[64][40];   // [colL][rowL], 8B-aligned rows

    f32x4 acc[2] = {};

    const unsigned short* a0 = A  + (size_t)(m0 + wr * 16 + tl) * lda + g * 8;
    const unsigned short* b0 = WT + (size_t)(n0 + wc * 32 + tl) * K + g * 8;
    const unsigned short* b1 = b0 + (size_t)16 * K;

    for (int k0 = 0; k0 < K; k0 += 32) {
        bf16x8 af  = ldb8(a0 + k0);
        bf16x8 bf0 = ldb8(b0 + k0), bf1 = ldb8(b1 + k0);
        acc[0] = __builtin_amdgcn_mfma_f32_16x16x32_bf16(af, bf0, acc[0], 0, 0, 0);
        acc[1] = __builtin_amdgcn_mfma_f32_16x16x32_bf16(af, bf1, acc[1], 0, 0, 0);
    }

    const float* bias = which == 0 ? bq : which == 1 ? bk : bv;
    const float sc = which == 0 ? qscale : 1.f;

    if (which < 2) {
        unsigned short* dst = which == 0 ? qb : kb;
        #pragma unroll
        for (int c16 = 0; c16 < 2; ++c16)
            #pragma unroll
            for (int reg = 0; reg < 4; ++reg) {
                int row = m0 + wr * 16 + g * 4 + reg;
                int col = (n0 & 255) + wc * 32 + c16 * 16 + tl;
                dst[(size_t)row * Cc + col] = f2b((acc[c16][reg] + bias[col]) * sc);
            }
    } else {
        #pragma unroll
        for (int c16 = 0; c16 < 2; ++c16)
            #pragma unroll
            for (int reg = 0; reg < 4; ++reg) {
                int colL = wc * 32 + c16 * 16 + tl;
                int rowL = wr * 16 + g * 4 + reg;
                vtile[colL][rowL] = f2b(acc[c16][reg] + bias[(n0 & 255) + colL]);
            }
        __syncthreads();
        int clocal = t >> 2, q = t & 3;
        int colg = (n0 & 255) + clocal;
        int hh = colg >> 5, dd = colg & 31;
        int bg = m0 >> 10, nb = (m0 & 1023) + q * 8;
        ushort4 u0 = *(ushort4*)&vtile[clocal][q * 8];
        ushort4 u1 = *(ushort4*)&vtile[clocal][q * 8 + 4];
        unsigned short* dst = vTb + ((size_t)((bg * Hh + hh) * DKh + dd)) * Nn + nb;
        *(ushort4*)dst = u0;
        *(ushort4*)(dst + 4) = u1;
    }
}

// ---------------- BN apply (single, float4) ----------------
__global__ __launch_bounds__(256) void bn_apply_k(
    const float* __restrict__ h, const float* __restrict__ gsum,
    const float* __restrict__ gsq, const float* __restrict__ gamma,
    const float* __restrict__ beta, float* __restrict__ outf)
{
    size_t i4 = ((size_t)blockIdx.x * 256 + threadIdx.x) * 4;
    int ch = (int)(i4 & (Cc - 1));
    float4 hv = *(const float4*)(h + i4);
    float4 sm = *(const float4*)(gsum + ch);
    float4 sq = *(const float4*)(gsq + ch);
    float4 ga = *(const float4*)(gamma + ch);
    float4 be = *(const float4*)(beta + ch);
    float4 o;
    {
        float m = sm.x * (1.f / BNn), var = sq.x * (1.f / BNn) - m * m;
        o.x = (hv.x - m) * rsqrtf(var + EPSV) * ga.x + be.x;
    }
    {
        float m = sm.y * (1.f / BNn), var = sq.y * (1.f / BNn) - m * m;
        o.y = (hv.y - m) * rsqrtf(var + EPSV) * ga.y + be.y;
    }
    {
        float m = sm.z * (1.f / BNn), var = sq.z * (1.f / BNn) - m * m;
        o.z = (hv.z - m) * rsqrtf(var + EPSV) * ga.z + be.z;
    }
    {
        float m = sm.w * (1.f / BNn), var = sq.w * (1.f / BNn) - m * m;
        o.w = (hv.w - m) * rsqrtf(var + EPSV) * ga.w + be.w;
    }
    *(float4*)(outf + i4) = o;
}

// ---------------- fused BN1+BN2 apply (float4) ----------------
__global__ __launch_bounds__(256) void bn_apply12_k(
    const float* __restrict__ h1pre, const float* __restrict__ h2pre,
    const float* __restrict__ stats,   // [sum1|sq1|sum2|sq2] each 256
    const float* __restrict__ g1, const float* __restrict__ be1,
    const float* __restrict__ g2, const float* __restrict__ be2,
    float* __restrict__ outf, unsigned short* __restrict__ outb)
{
    size_t i4 = ((size_t)blockIdx.x * 256 + threadIdx.x) * 4;
    int ch = (int)(i4 & (Cc - 1));
    float4 h1 = *(const float4*)(h1pre + i4);
    float4 h2 = *(const float4*)(h2pre + i4);
    float4 s1m = *(const float4*)(stats + ch);
    float4 s1q = *(const float4*)(stats + 256 + ch);
    float4 s2m = *(const float4*)(stats + 512 + ch);
    float4 s2q = *(const float4*)(stats + 768 + ch);
    float4 G1 = *(const float4*)(g1 + ch),  B1 = *(const float4*)(be1 + ch);
    float4 G2 = *(const float4*)(g2 + ch),  B2 = *(const float4*)(be2 + ch);
    float4 o;
    #define BN12C(comp) { \
        float m1 = s1m.comp * (1.f / BNn), v1 = s1q.comp * (1.f / BNn) - m1 * m1; \
        float m2 = s2m.comp * (1.f / BNn), v2 = s2q.comp * (1.f / BNn) - m2 * m2; \
        o.comp = (h1.comp - m1) * rsqrtf(v1 + EPSV) * G1.comp + B1.comp \
               + (h2.comp - m2) * rsqrtf(v2 + EPSV) * G2.comp + B2.comp; }
    BN12C(x) BN12C(y) BN12C(z) BN12C(w)
    #undef BN12C
    *(float4*)(outf + i4) = o;
    ushort4 pk;
    pk.x = f2b(o.x); pk.y = f2b(o.y); pk.z = f2b(o.z); pk.w = f2b(o.w);
    *(ushort4*)(outb + i4) = pk;
}

// ---------------- MFMA flash attention, transposed scores, m-split x4 ----------------
__global__ __launch_bounds__(512) void attn_k(
    const unsigned short* __restrict__ q, const unsigned short* __restrict__ k,
    const unsigned short* __restrict__ vT, const float* __restrict__ sph,
    float* __restrict__ op0, float* __restrict__ op1,
    float* __restrict__ op2, float* __restrict__ op3,
    float* __restrict__ lpart)
{
    const int n0 = blockIdx.x * 16;
    const int mc = blockIdx.y;
    const int b  = blockIdx.z;
    const int t  = threadIdx.x;
    const int w  = t >> 6;
    const int lane = t & 63;
    const int tl = lane & 15, g = lane >> 4;

    __shared__ float Sph[16][68];
    __shared__ unsigned short Ps[Hh][16][72];

    bf16x8 qf = ldb8(q + ((size_t)(b * Nn + n0 + tl)) * Cc + w * DKh + g * 8);

    float lsum = 0.f;
    f32x4 oacc[2] = {};

    const unsigned short* kbase = k + ((size_t)(b * Nn) + tl) * Cc + w * DKh + g * 8;
    const unsigned short* vbase = vT + ((size_t)((b * Hh + w) * DKh) + tl) * Nn + g * 8;
    const float* sbase = sph + ((size_t)b * Nn + n0) * Nn;

    for (int m0 = mc * MCH; m0 < mc * MCH + MCH; m0 += 64) {
        __syncthreads();
        {
            int r1 = t >> 6, c1 = t & 63;
            Sph[r1][c1]     = sbase[(size_t)r1 * Nn + m0 + c1];
            Sph[r1 + 8][c1] = sbase[(size_t)(r1 + 8) * Nn + m0 + c1];
        }
        __syncthreads();

        f32x4 st[4];
        #pragma unroll
        for (int mg = 0; mg < 4; ++mg) {
            bf16x8 ka = ldb8(kbase + (size_t)(m0 + mg * 16) * Cc);
            f32x4 z = {0.f, 0.f, 0.f, 0.f};
            st[mg] = __builtin_amdgcn_mfma_f32_16x16x32_bf16(ka, qf, z, 0, 0, 0);
        }

        #pragma unroll
        for (int mg = 0; mg < 4; ++mg) {
            float4 sp = *(const float4*)&Sph[tl][mg * 16 + g * 4];
            float p0 = exp2f(st[mg][0] * sp.x);
            float p1 = exp2f(st[mg][1] * sp.y);
            float p2 = exp2f(st[mg][2] * sp.z);
            float p3 = exp2f(st[mg][3] * sp.w);
            lsum += (p0 + p1) + (p2 + p3);
            ushort4 pk;
            pk.x = f2b(p0); pk.y = f2b(p1); pk.z = f2b(p2); pk.w = f2b(p3);
            *(ushort4*)&Ps[w][tl][mg * 16 + g * 4] = pk;
        }

        #pragma unroll
        for (int ks = 0; ks < 2; ++ks) {
            bf16x8 pa = ldb8(&Ps[w][tl][ks * 32 + g * 8]);
            #pragma unroll
            for (int cg = 0; cg < 2; ++cg) {
                bf16x8 vb = ldb8(vbase + (size_t)(cg * 16) * Nn + m0 + ks * 32);
                oacc[cg] = __builtin_amdgcn_mfma_f32_16x16x32_bf16(pa, vb, oacc[cg], 0, 0, 0);
            }
        }
    }

    lsum += __shfl_xor(lsum, 16);
    lsum += __shfl_xor(lsum, 32);
    if (g == 0)
        lpart[((size_t)mc * BNn + b * Nn + n0 + tl) * Hh + w] = lsum;

    float* op = mc == 0 ? op0 : mc == 1 ? op1 : mc == 2 ? op2 : op3;
    #pragma unroll
    for (int r = 0; r < 4; ++r)
        #pragma unroll
        for (int cg = 0; cg < 2; ++cg)
            op[((size_t)(b * Nn + n0 + g * 4 + r)) * Cc + w * DKh + cg * 16 + tl]
                = oacc[cg][r];
}

// ---------------- combine m-split partials (float4) ----------------
__global__ __launch_bounds__(256) void attn_combine_k(
    const float* __restrict__ op0, const float* __restrict__ op1,
    const float* __restrict__ op2, const float* __restrict__ op3,
    const float* __restrict__ lpart, unsigned short* __restrict__ ob)
{
    size_t i4 = ((size_t)blockIdx.x * 256 + threadIdx.x) * 4;
    int row = (int)(i4 >> 8);
    int h = (int)((i4 & 255) >> 5);
    float4 a = *(const float4*)(op0 + i4);
    float4 b = *(const float4*)(op1 + i4);
    float4 c = *(const float4*)(op2 + i4);
    float4 d = *(const float4*)(op3 + i4);
    float l = lpart[(size_t)row * Hh + h]
            + lpart[((size_t)BNn + row) * Hh + h]
            + lpart[((size_t)2 * BNn + row) * Hh + h]
            + lpart[((size_t)3 * BNn + row) * Hh + h];
    float inv = 1.f / l;
    ushort4 pk;
    pk.x = f2b((a.x + b.x + c.x + d.x) * inv);
    pk.y = f2b((a.y + b.y + c.y + d.y) * inv);
    pk.z = f2b((a.z + b.z + c.z + d.z) * inv);
    pk.w = f2b((a.w + b.w + c.w + d.w) * inv);
    *(ushort4*)(ob + i4) = pk;
}

// ---------------- launch ----------------
extern "C" void kernel_launch(void* const* d_in, const int* in_sizes, int n_in,
                              void* d_out, int out_size, void* d_ws, size_t ws_size,
                              hipStream_t stream)
{
    const float* x   = (const float*)d_in[0];
    const int*   ei  = (const int*)  d_in[1];
    const float* sph = (const float*)d_in[2];
    const float* Wr  = (const float*)d_in[3];
    const float* Wn  = (const float*)d_in[4];
    const float* Wq  = (const float*)d_in[5];
    const float* bq  = (const float*)d_in[6];
    const float* Wk  = (const float*)d_in[7];
    const float* bk  = (const float*)d_in[8];
    const float* Wv  = (const float*)d_in[9];
    const float* bv  = (const float*)d_in[10];
    const float* Wo  = (const float*)d_in[11];
    const float* bo  = (const float*)d_in[12];
    const float* W1  = (const float*)d_in[13];
    const float* b1  = (const float*)d_in[14];
    const float* W2  = (const float*)d_in[15];
    const float* b2  = (const float*)d_in[16];
    const float* g1  = (const float*)d_in[17];
    const float* be1 = (const float*)d_in[18];
    const float* g2  = (const float*)d_in[19];
    const float* be2 = (const float*)d_in[20];
    const float* g3  = (const float*)d_in[21];
    const float* be3 = (const float*)d_in[22];
    float* out = (float*)d_out;

    const size_t SL = (size_t)BNn * Cc;  // 2M elements

    float* ws = (float*)d_ws;
    float* s1 = ws;                  // attn O-partial 0 -> outsum (fp32)
    float* s2 = s1 + SL;             // h1pre (alive until bn_apply12) -> out2
    float* s3 = s2 + SL;             // attn O-partial 1 -> h2pre

    int*   deg      = (int*)(s3 + SL);          // 8192
    float* statsAll = (float*)(deg + 8192);     // 1536
    int*   rowst    = (int*)(statsAll + 1536);  // 8192 (+pad)
    int*   cursor   = rowst + 8256;             // 8192
    int*   eidx     = cursor + 8192;            // 131072

    unsigned short* xcat = (unsigned short*)(eidx + 131072); // [8192][512]; reused as
                                                             // opart2 (float) then hid
    unsigned short* qb   = xcat + 2 * SL;
    unsigned short* kb   = qb + SL;                          // reused as osb
    unsigned short* vTb  = kb + SL;
    unsigned short* ob   = vTb + SL;
    unsigned short* osb  = kb;
    unsigned short* hid  = xcat;
    float* opart2 = (float*)xcat;

    unsigned short* WcatT = ob + SL;          // 256x512
    unsigned short* WqT   = WcatT + 131072;   // WqT|WkT|WvT contiguous = [768][256]
    unsigned short* WkT   = WqT + 65536;
    unsigned short* WvT   = WkT + 65536;
    unsigned short* WoT   = WvT + 65536;
    unsigned short* W1T   = WoT + 65536;
    unsigned short* W2T   = W1T + 131072;
    float* lpart  = (float*)(W2T + 131072);   // [MSPLIT][BNn][Hh] fp32 = 1 MB
    float* opart3 = lpart + (size_t)MSPLIT * BNn * Hh;   // 8 MB

    dim3 gN256(4, 256);
    dim3 gN512(8, 256);
    dim3 gQKV(12, 256);

    const float QSCALE = 0.17677669529663687f * 1.4426950408889634f;

    // 1) zero deg + all BN stats in one memset
    hipMemsetAsync(deg, 0, (8192 + 1536) * sizeof(float), stream);
    // 2) fused converts + histogram
    prep_k<<<5120, 256, 0, stream>>>(x, xcat, Wr, Wn, Wq, Wk, Wv, Wo, W1, W2,
                                     WcatT, WqT, WkT, WvT, WoT, W1T, W2T, ei, deg);
    // 3-5) CSR scan / place / gather
    scan_k<<<1, 256, 0, stream>>>(deg, rowst, cursor);
    place_k<<<Ee / 256, 256, 0, stream>>>(ei, cursor, eidx);
    gather_k<<<BNn, 64, 0, stream>>>(x, rowst, deg, eidx, xcat);
    // 6) h1pre = [x|aggx] @ [Wr;Wn]^T + x  (K=512) -> s2, + fused BN1 stats
    gemm_mfma_k<<<gN256, 256, 0, stream>>>(xcat, WcatT, nullptr, x,
                                           s2, nullptr, statsAll, statsAll + 256,
                                           BNn, 512, 512, Cc, 0, 1.f);
    // 7) fused q,k,v projection
    qkv_gemm_k<<<gQKV, 256, 0, stream>>>(xcat, WqT, bq, bk, bv, qb, kb, vTb, QSCALE);
    // 8) attention -> 4 O-partials + lpart
    attn_k<<<dim3(Nn / 16, MSPLIT, Bg), 512, 0, stream>>>(qb, kb, vTb, sph,
                                                          s1, s3, opart2, opart3, lpart);
    // 9) combine -> ob (bf16)
    attn_combine_k<<<(int)(SL / 1024), 256, 0, stream>>>(s1, s3, opart2, opart3,
                                                         lpart, ob);
    // 10) h2pre = o @ Wo + bo + x -> s3, + fused BN2 stats
    gemm_mfma_k<<<gN256, 256, 0, stream>>>(ob, WoT, bo, x,
                                           s3, nullptr, statsAll + 512, statsAll + 768,
                                           BNn, Cc, Cc, Cc, 0, 1.f);
    // 11) outsum = bn1(h1pre) + bn2(h2pre) -> s1 (fp32) + osb (bf16)
    bn_apply12_k<<<(int)(SL / 1024), 256, 0, stream>>>(s2, s3, statsAll,
                                                       g1, be1, g2, be2, s1, osb);
    // 12) hidden = relu(outsum @ W1 + b1) -> hid (bf16)
    gemm_mfma_k<<<gN512, 256, 0, stream>>>(osb, W1T, b1, nullptr,
                                           nullptr, hid, nullptr, nullptr,
                                           BNn, Cc, Cc, 2 * Cc, 1, 1.f);
    // 13) out2 = hidden @ W2 + b2 + outsum -> s2, + fused BN3 stats
    gemm_mfma_k<<<gN256, 256, 0, stream>>>(hid, W2T, b2, s1,
                                           s2, nullptr, statsAll + 1024, statsAll + 1280,
                                           BNn, 2 * Cc, 2 * Cc, Cc, 0, 1.f);
    // 14) d_out = BN3(out2)
    bn_apply_k<<<(int)(SL / 1024), 256, 0, stream>>>(s2, statsAll + 1024,
                                                     statsAll + 1280, g3, be3, out);
}